// Round 10
// baseline (494.664 us; speedup 1.0000x reference)
//
#include <hip/hip_runtime.h>
#include <cstddef>
#include <cstdint>

#define NN 20000

typedef short frag16 __attribute__((ext_vector_type(8)));
typedef float f32x4 __attribute__((ext_vector_type(4)));

__device__ inline unsigned short f32_to_bf16(float f) {
    uint32_t u = __float_as_uint(f);
    u += 0x7FFFu + ((u >> 16) & 1u);
    return (unsigned short)(u >> 16);
}

__device__ inline float bf1(unsigned short h) {
    return __uint_as_float((uint32_t)h << 16);
}

// ===================== fused prep =====================
// sections (256 thr each), edge/atomic section FIRST so its latency overlaps:
//   [0,eb)             edge count + fixed-stride CSR fill (stride 64)
//   [eb,eb+64)         T[(b,s),f1] = sum_s' W1[s',s]*x[b,s',f1]  (fp32 out)
//   [eb+64,+2512)      nsum bf16 (20096x512, pad rows zero), 16 shorts/thread
//   [.. +32)           transpose gcn_W l=1,2 -> WT (bf16)
//   [.. +128)          cvec[b,s] = 2*dot(x[b,s,:],bp)
__global__ __launch_bounds__(256) void prep(
    const float* __restrict__ nodes, const float* __restrict__ x,
    const float* __restrict__ gcn_W, const float* __restrict__ bp,
    const int* __restrict__ src, const int* __restrict__ dst,
    unsigned short* __restrict__ nsum16, unsigned short* __restrict__ WT,
    float* __restrict__ Tf, float* __restrict__ cvec,
    int* __restrict__ cnt, int* __restrict__ csr, int E)
{
    __shared__ __align__(16) char shmem[8704];
    const int blk = blockIdx.x, tid = threadIdx.x;
    const int eb = (E + 255) >> 8;

    if (blk < eb) {                          // ---- count + CSR fill ----
        int e = blk * 256 + tid;
        if (e < E) {
            int d = dst[e];
            int pos = atomicAdd(&cnt[d], 1);
            if (pos < 64) csr[(d << 6) + pos] = src[e];
        }
    } else if (blk < eb + 64) {              // ---- T section (fp32) ----
        float* As = (float*)shmem;           // [16][64]  (k, m=s)
        float* Bs = As + 1024;               // [16][64]  (k, n=f1)
        int t = blk - eb;
        int b = t >> 5, rem = t & 31;
        int s0 = (rem >> 3) * 64, f0 = (rem & 7) * 64;
        const float* W1 = gcn_W;             // [s'][s] row-major
        const float* xb = x + (size_t)b * 256 * 512;
        int kk = tid >> 4, c4 = (tid & 15) << 2;
        int tm = tid >> 4, tn = tid & 15;
        float acc[4][4] = {};
        for (int k0 = 0; k0 < 256; k0 += 16) {
            float4 av = *(const float4*)(W1 + (size_t)(k0 + kk) * 256 + s0 + c4);
            float4 bv = *(const float4*)(xb + (size_t)(k0 + kk) * 512 + f0 + c4);
            __syncthreads();
            *(float4*)&As[kk * 64 + c4] = av;
            *(float4*)&Bs[kk * 64 + c4] = bv;
            __syncthreads();
            #pragma unroll
            for (int k = 0; k < 16; ++k) {
                float a[4], bb[4];
                *(float4*)a  = *(const float4*)&As[k * 64 + (tm << 2)];
                *(float4*)bb = *(const float4*)&Bs[k * 64 + (tn << 2)];
                #pragma unroll
                for (int i = 0; i < 4; ++i)
                    #pragma unroll
                    for (int j = 0; j < 4; ++j) acc[i][j] += a[i] * bb[j];
            }
        }
        #pragma unroll
        for (int i = 0; i < 4; ++i) {
            int row = b * 256 + s0 + (tm << 2) + i;
            *(float4*)(Tf + (size_t)row * 512 + f0 + (tn << 2)) =
                make_float4(acc[i][0], acc[i][1], acc[i][2], acc[i][3]);
        }
    } else if (blk < eb + 64 + 2512) {       // ---- nsum, 16 shorts/thread ----
        int g = (blk - eb - 64) * 256 + tid; // [0, 643072)
        int n = g >> 5, c = (g & 31) << 4;
        uint4 o0, o1;
        if (n < NN) {
            const float* r0 = nodes + (size_t)n * 1024 + c;
            const float* r1 = r0 + 512;
            float4 a0 = *(const float4*)(r0 + 0),  a1 = *(const float4*)(r0 + 4);
            float4 a2 = *(const float4*)(r0 + 8),  a3 = *(const float4*)(r0 + 12);
            float4 b0 = *(const float4*)(r1 + 0),  b1 = *(const float4*)(r1 + 4);
            float4 b2 = *(const float4*)(r1 + 8),  b3 = *(const float4*)(r1 + 12);
            o0.x = ((uint32_t)f32_to_bf16(a0.y + b0.y) << 16) | f32_to_bf16(a0.x + b0.x);
            o0.y = ((uint32_t)f32_to_bf16(a0.w + b0.w) << 16) | f32_to_bf16(a0.z + b0.z);
            o0.z = ((uint32_t)f32_to_bf16(a1.y + b1.y) << 16) | f32_to_bf16(a1.x + b1.x);
            o0.w = ((uint32_t)f32_to_bf16(a1.w + b1.w) << 16) | f32_to_bf16(a1.z + b1.z);
            o1.x = ((uint32_t)f32_to_bf16(a2.y + b2.y) << 16) | f32_to_bf16(a2.x + b2.x);
            o1.y = ((uint32_t)f32_to_bf16(a2.w + b2.w) << 16) | f32_to_bf16(a2.z + b2.z);
            o1.z = ((uint32_t)f32_to_bf16(a3.y + b3.y) << 16) | f32_to_bf16(a3.x + b3.x);
            o1.w = ((uint32_t)f32_to_bf16(a3.w + b3.w) << 16) | f32_to_bf16(a3.z + b3.z);
        } else {
            o0 = make_uint4(0, 0, 0, 0); o1 = o0;
        }
        *(uint4*)(nsum16 + (size_t)n * 512 + c) = o0;
        *(uint4*)(nsum16 + (size_t)n * 512 + c + 8) = o1;
    } else if (blk < eb + 64 + 2512 + 32) {  // ---- WT transpose (l=1,2) ----
        unsigned short (*tsh)[68] = (unsigned short(*)[68])shmem;
        int t = blk - eb - 64 - 2512;
        int l = t >> 4, rem = t & 15;
        int c0 = (rem & 3) * 64, r0 = (rem >> 2) * 64;
        const float* inp = gcn_W + (size_t)(l + 1) * 65536;
        unsigned short* outp = WT + (size_t)l * 65536;
        int tx = tid & 15, ty = tid >> 4;
        #pragma unroll
        for (int rr = 0; rr < 4; ++rr) {
            int r = ty * 4 + rr;
            float4 v = *(const float4*)(inp + (size_t)(r0 + r) * 256 + c0 + tx * 4);
            tsh[tx * 4 + 0][r] = f32_to_bf16(v.x);
            tsh[tx * 4 + 1][r] = f32_to_bf16(v.y);
            tsh[tx * 4 + 2][r] = f32_to_bf16(v.z);
            tsh[tx * 4 + 3][r] = f32_to_bf16(v.w);
        }
        __syncthreads();
        #pragma unroll
        for (int cc = 0; cc < 4; ++cc) {
            int c = ty * 4 + cc;
            ushort4 o = *(ushort4*)&tsh[c][tx * 4];
            *(ushort4*)(outp + (size_t)(c0 + c) * 256 + r0 + tx * 4) = o;
        }
    } else {                                 // ---- cvec ----
        int row = (blk - eb - 64 - 2512 - 32) * 4 + (tid >> 6);
        int lane = tid & 63;
        const float* xr = x + (size_t)row * 512;
        float s = 0.f;
        #pragma unroll
        for (int k = 0; k < 512; k += 64) s += xr[k + lane] * bp[k + lane];
        #pragma unroll
        for (int off = 32; off; off >>= 1) s += __shfl_down(s, off);
        if (lane == 0) cvec[row] = 2.0f * s;
    }
}

// ===================== mid: U = T @ Wp (bf16 out) + cb2 = W1^T . cvec ==============
__global__ __launch_bounds__(256) void mid(
    const float* __restrict__ Tf, const float* __restrict__ Wp,
    const float* __restrict__ gcn_W, const float* __restrict__ cvec,
    unsigned short* __restrict__ Ub, float* __restrict__ cb2)
{
    const int blk = blockIdx.x, tid = threadIdx.x;
    if (blk >= 64) {                         // ---- cb2 ----
        int idx = (blk - 64) * 256 + tid;    // [0,512)
        int b = idx >> 8, s = idx & 255;
        float sum = 0.f;
        for (int sp = 0; sp < 256; ++sp)
            sum += gcn_W[(size_t)sp * 256 + s] * cvec[b * 256 + sp];
        cb2[idx] = sum;
        return;
    }
    __shared__ float As[16][68];
    __shared__ float Bs[16][64];
    int bm = (blk >> 3) * 64, bn = (blk & 7) * 64;
    int arow = tid >> 2, acol = (tid & 3) << 2;
    int brow = tid >> 4, bcol = (tid & 15) << 2;
    int tm = tid >> 4, tn = tid & 15;
    float acc[4][4] = {};
    for (int k0 = 0; k0 < 512; k0 += 16) {
        float4 av = *(const float4*)(Tf + (size_t)(bm + arow) * 512 + k0 + acol);
        float4 bv = *(const float4*)(Wp + (size_t)(k0 + brow) * 512 + bn + bcol);
        __syncthreads();
        As[acol + 0][arow] = av.x; As[acol + 1][arow] = av.y;
        As[acol + 2][arow] = av.z; As[acol + 3][arow] = av.w;
        *(float4*)&Bs[brow][bcol] = bv;
        __syncthreads();
        #pragma unroll
        for (int k = 0; k < 16; ++k) {
            float a[4], b[4];
            *(float4*)a = *(const float4*)&As[k][tm << 2];
            *(float4*)b = *(const float4*)&Bs[k][tn << 2];
            #pragma unroll
            for (int i = 0; i < 4; ++i)
                #pragma unroll
                for (int j = 0; j < 4; ++j) acc[i][j] += a[i] * b[j];
        }
    }
    #pragma unroll
    for (int i = 0; i < 4; ++i) {
        int row = bm + (tm << 2) + i;
        ushort4 o;
        o.x = f32_to_bf16(acc[i][0]); o.y = f32_to_bf16(acc[i][1]);
        o.z = f32_to_bf16(acc[i][2]); o.w = f32_to_bf16(acc[i][3]);
        *(ushort4*)(Ub + (size_t)row * 512 + bn + (tn << 2)) = o;
    }
}

// ===================== bf16 MFMA GEMM =====================
// C = A[M,K] @ BT[N,K]^T, bf16 in/out, fp32 accum.
// mode 1: hw1: C[m*512+n] = (acc + cb2[n]) * rsqrt(cnt[m]+1)   (m = node)
// mode 2: N=256, m carries b: node=m-b*NN; C[node*512+(b<<8)+n] = acc*rsqrt(cnt[node]+1)
__global__ __launch_bounds__(256) void mgemm(
    const unsigned short* __restrict__ A, const unsigned short* __restrict__ BT,
    int K, int N, int mode,
    const float* __restrict__ cb2, const int* __restrict__ cnt,
    unsigned short* __restrict__ C)
{
    __shared__ __align__(16) unsigned short As[128 * 32];
    __shared__ __align__(16) unsigned short Bs[128 * 32];
    const int bm = blockIdx.y * 128, bn = blockIdx.x * 128;
    const int tid = threadIdx.x;
    const int lane = tid & 63, w = tid >> 6;
    const int wm = (w >> 1) << 6, wn = (w & 1) << 6;
    const int r = lane & 15, q = lane >> 4;

    f32x4 acc[4][4] = {};

    for (int k0 = 0; k0 < K; k0 += 32) {
        __syncthreads();
        #pragma unroll
        for (int t = 0; t < 2; ++t) {
            int c = t * 256 + w * 64 + lane;
            int row = c >> 2, col = (c & 3) << 3;
            __builtin_amdgcn_global_load_lds(
                (const __attribute__((address_space(1))) void*)(A + (size_t)(bm + row) * K + k0 + col),
                (__attribute__((address_space(3))) void*)(As + (size_t)(t * 256 + w * 64) * 8),
                16, 0, 0);
            __builtin_amdgcn_global_load_lds(
                (const __attribute__((address_space(1))) void*)(BT + (size_t)(bn + row) * K + k0 + col),
                (__attribute__((address_space(3))) void*)(Bs + (size_t)(t * 256 + w * 64) * 8),
                16, 0, 0);
        }
        __syncthreads();
        frag16 af[4], bf[4];
        #pragma unroll
        for (int i = 0; i < 4; ++i)
            af[i] = *(const frag16*)(As + ((wm + i * 16 + r) << 5) + (q << 3));
        #pragma unroll
        for (int j = 0; j < 4; ++j)
            bf[j] = *(const frag16*)(Bs + ((wn + j * 16 + r) << 5) + (q << 3));
        #pragma unroll
        for (int i = 0; i < 4; ++i)
            #pragma unroll
            for (int j = 0; j < 4; ++j)
                acc[i][j] = __builtin_amdgcn_mfma_f32_16x16x32_bf16(af[i], bf[j], acc[i][j], 0, 0, 0);
    }

    // C/D layout: col = lane&15 (r), row = q*4 + reg
    #pragma unroll
    for (int i = 0; i < 4; ++i) {
        #pragma unroll
        for (int rg = 0; rg < 4; ++rg) {
            int m = bm + wm + i * 16 + (q << 2) + rg;
            float sc;
            int b2 = 0, node = m;
            if (mode == 1) {
                int nc = m > NN - 1 ? NN - 1 : m;
                sc = rsqrtf((float)cnt[nc] + 1.0f);
            } else {
                b2 = m >= NN;
                node = m - b2 * NN;
                int nc = node > NN - 1 ? NN - 1 : node;
                sc = rsqrtf((float)cnt[nc] + 1.0f);
                if (node > 20095) node = 20095;     // pad rows: stay in-buffer
            }
            #pragma unroll
            for (int j = 0; j < 4; ++j) {
                int n = bn + wn + j * 16 + r;
                if (mode == 1) {
                    float v = (acc[i][j][rg] + cb2[n]) * sc;
                    C[(size_t)m * 512 + n] = f32_to_bf16(v);
                } else {
                    float v = acc[i][j][rg] * sc;
                    C[(size_t)node * 512 + (b2 << 8) + n] = f32_to_bf16(v);
                }
            }
        }
    }
}

// ===================== GCN aggregation: channel-chunked, XCD-affine =====================
// hw: [20096][512] bf16 (cols 0..255 b0, 256..511 b1), rows pre-scaled by dinv[src].
// grid 40000: chunk c = blk & 7 (64 channels; ~2.56 MB working set -> one XCD's L2),
// node group = blk >> 3 (4 nodes/block, 1 per wave). Lane ch = c*64+lane.
// Last layer (out != null): per-chunk partial dot with w_bp -> atomicAdd into out.
__global__ __launch_bounds__(256) void aggregate_c(
    const unsigned short* __restrict__ hw, const int* __restrict__ cnt,
    const int* __restrict__ csr, const float* __restrict__ bias,
    unsigned short* __restrict__ hout,
    const float* __restrict__ w_bp, const float* __restrict__ b_bp,
    float* __restrict__ out)
{
    int blk = blockIdx.x;
    int c = blk & 7;                       // chunk -> XCD (round-robin heuristic)
    int n = (blk >> 3) * 4 + (threadIdx.x >> 6);   // node 0..19999
    int lane = threadIdx.x & 63;
    int ch = (c << 6) + lane;              // combined channel [0,512)
    const unsigned short* colp = hw + ch;

    float acc = bf1(colp[(size_t)n * 512]);          // self loop
    int deg = cnt[n]; if (deg > 64) deg = 64;
    const int* cp = csr + (n << 6);
    int e = 0;
    for (; e + 8 <= deg; e += 8) {
        int4 c0 = *(const int4*)(cp + e);
        int4 c1 = *(const int4*)(cp + e + 4);
        unsigned short u0 = colp[(size_t)c0.x * 512];
        unsigned short u1 = colp[(size_t)c0.y * 512];
        unsigned short u2 = colp[(size_t)c0.z * 512];
        unsigned short u3 = colp[(size_t)c0.w * 512];
        unsigned short u4 = colp[(size_t)c1.x * 512];
        unsigned short u5 = colp[(size_t)c1.y * 512];
        unsigned short u6 = colp[(size_t)c1.z * 512];
        unsigned short u7 = colp[(size_t)c1.w * 512];
        acc += ((bf1(u0) + bf1(u1)) + (bf1(u2) + bf1(u3)))
             + ((bf1(u4) + bf1(u5)) + (bf1(u6) + bf1(u7)));
    }
    if (e + 4 <= deg) {
        int4 c0 = *(const int4*)(cp + e);
        unsigned short u0 = colp[(size_t)c0.x * 512];
        unsigned short u1 = colp[(size_t)c0.y * 512];
        unsigned short u2 = colp[(size_t)c0.z * 512];
        unsigned short u3 = colp[(size_t)c0.w * 512];
        acc += (bf1(u0) + bf1(u1)) + (bf1(u2) + bf1(u3));
        e += 4;
    }
    for (; e < deg; ++e)
        acc += bf1(colp[(size_t)cp[e] * 512]);

    float dn = rsqrtf((float)deg + 1.0f);
    int s = ch & 255;                      // channel within batch
    int b = c >> 2;                        // batch
    float v = fmaf(dn, acc, bias[s]);
    v = v > 0.f ? v : 0.01f * v;

    if (out) {
        float p = v * w_bp[s];
        #pragma unroll
        for (int off = 32; off; off >>= 1) p += __shfl_xor(p, off);
        if (lane == 0) {
            if ((c & 3) == 0) p += b_bp[0];
            atomicAdd(&out[b * NN + n], p);
        }
    } else {
        hout[((size_t)(b * NN + n)) * 256 + s] = f32_to_bf16(v);
    }
}

extern "C" void kernel_launch(void* const* d_in, const int* in_sizes, int n_in,
                              void* d_out, int out_size, void* d_ws, size_t ws_size,
                              hipStream_t stream) {
    const float* x     = (const float*)d_in[0];
    const float* nodes = (const float*)d_in[1];
    const int*   eidx  = (const int*)d_in[2];
    const float* Wp    = (const float*)d_in[3];
    const float* bp    = (const float*)d_in[4];
    const float* gcn_W = (const float*)d_in[5];
    const float* gcn_b = (const float*)d_in[6];
    const float* w_bp  = (const float*)d_in[7];
    const float* b_bp  = (const float*)d_in[8];
    const int E = in_sizes[2] / 2;

    char* w = (char*)d_ws;
    auto alloc = [&](size_t bytes) { char* p = w; w += (bytes + 255) & ~(size_t)255; return p; };
    unsigned short* nsum16 = (unsigned short*)alloc((size_t)20096 * 512 * 2);
    unsigned short* hw16   = (unsigned short*)alloc((size_t)20096 * 512 * 2);
    unsigned short* hA     = (unsigned short*)alloc((size_t)40192 * 256 * 2);
    unsigned short* hB     = (unsigned short*)alloc((size_t)40192 * 256 * 2);
    float* Tf  = (float*)alloc((size_t)512 * 512 * 4);
    unsigned short* Ub = (unsigned short*)alloc((size_t)512 * 512 * 2);
    unsigned short* WT = (unsigned short*)alloc((size_t)2 * 256 * 256 * 2);
    float* cvec = (float*)alloc(512 * 4);
    float* cb2  = (float*)alloc(512 * 4);
    int*   cnt  = (int*)alloc((size_t)NN * 4);
    int*   csr  = (int*)alloc((size_t)NN * 64 * 4);

    hipMemsetAsync(cnt, 0, (size_t)NN * 4, stream);
    hipMemsetAsync(d_out, 0, (size_t)out_size * 4, stream);   // atomic accumulation target

    const int cntBlks = (E + 255) / 256;
    prep<<<cntBlks + 64 + 2512 + 32 + 128, 256, 0, stream>>>(
        nodes, x, gcn_W, bp, eidx, eidx + E, nsum16, WT, Tf, cvec, cnt, csr, E);
    mid<<<66, 256, 0, stream>>>(Tf, Wp, gcn_W, cvec, Ub, cb2);

    // hw1[node,(b,s)] = (nsum @ U^T + cb2) * dinv[node]
    mgemm<<<dim3(4, 157), 256, 0, stream>>>(nsum16, Ub, 512, 512, 1, cb2, cnt, hw16);

    aggregate_c<<<40000, 256, 0, stream>>>(hw16, cnt, csr, gcn_b + 0, hA,
                                           w_bp, b_bp, nullptr);
    mgemm<<<dim3(2, 313), 256, 0, stream>>>(hA, WT, 256, 256, 2, nullptr, cnt, hw16);
    aggregate_c<<<40000, 256, 0, stream>>>(hw16, cnt, csr, gcn_b + 256, hB,
                                           w_bp, b_bp, nullptr);
    mgemm<<<dim3(2, 313), 256, 0, stream>>>(hB, WT + 65536, 256, 256, 2, nullptr, cnt, hw16);
    aggregate_c<<<40000, 256, 0, stream>>>(hw16, cnt, csr, gcn_b + 512, nullptr,
                                           w_bp, b_bp, (float*)d_out);
}

// Round 11
// 486.276 us; speedup vs baseline: 1.0172x; 1.0172x over previous
//
#include <hip/hip_runtime.h>
#include <cstddef>
#include <cstdint>

#define NN 20000

typedef short frag16 __attribute__((ext_vector_type(8)));
typedef float f32x4 __attribute__((ext_vector_type(4)));

__device__ inline unsigned short f32_to_bf16(float f) {
    uint32_t u = __float_as_uint(f);
    u += 0x7FFFu + ((u >> 16) & 1u);
    return (unsigned short)(u >> 16);
}

__device__ inline float4 dec4(uint2 v) {
    float4 r;
    r.x = __uint_as_float(v.x << 16);
    r.y = __uint_as_float(v.x & 0xffff0000u);
    r.z = __uint_as_float(v.y << 16);
    r.w = __uint_as_float(v.y & 0xffff0000u);
    return r;
}

// ===================== fused prep (unchanged structure) =====================
__global__ __launch_bounds__(256) void prep(
    const float* __restrict__ nodes, const float* __restrict__ x,
    const float* __restrict__ gcn_W, const float* __restrict__ bp,
    const int* __restrict__ src, const int* __restrict__ dst,
    unsigned short* __restrict__ nsum16, unsigned short* __restrict__ WT,
    float* __restrict__ Tf, float* __restrict__ cvec,
    int* __restrict__ cnt, int* __restrict__ csr, int E)
{
    __shared__ __align__(16) char shmem[8704];
    const int blk = blockIdx.x, tid = threadIdx.x;
    const int eb = (E + 255) >> 8;

    if (blk < eb) {                          // ---- count + CSR fill ----
        int e = blk * 256 + tid;
        if (e < E) {
            int d = dst[e];
            int pos = atomicAdd(&cnt[d], 1);
            if (pos < 64) csr[(d << 6) + pos] = src[e];
        }
    } else if (blk < eb + 64) {              // ---- T section (fp32) ----
        float* As = (float*)shmem;
        float* Bs = As + 1024;
        int t = blk - eb;
        int b = t >> 5, rem = t & 31;
        int s0 = (rem >> 3) * 64, f0 = (rem & 7) * 64;
        const float* W1 = gcn_W;
        const float* xb = x + (size_t)b * 256 * 512;
        int kk = tid >> 4, c4 = (tid & 15) << 2;
        int tm = tid >> 4, tn = tid & 15;
        float acc[4][4] = {};
        for (int k0 = 0; k0 < 256; k0 += 16) {
            float4 av = *(const float4*)(W1 + (size_t)(k0 + kk) * 256 + s0 + c4);
            float4 bv = *(const float4*)(xb + (size_t)(k0 + kk) * 512 + f0 + c4);
            __syncthreads();
            *(float4*)&As[kk * 64 + c4] = av;
            *(float4*)&Bs[kk * 64 + c4] = bv;
            __syncthreads();
            #pragma unroll
            for (int k = 0; k < 16; ++k) {
                float a[4], bb[4];
                *(float4*)a  = *(const float4*)&As[k * 64 + (tm << 2)];
                *(float4*)bb = *(const float4*)&Bs[k * 64 + (tn << 2)];
                #pragma unroll
                for (int i = 0; i < 4; ++i)
                    #pragma unroll
                    for (int j = 0; j < 4; ++j) acc[i][j] += a[i] * bb[j];
            }
        }
        #pragma unroll
        for (int i = 0; i < 4; ++i) {
            int row = b * 256 + s0 + (tm << 2) + i;
            *(float4*)(Tf + (size_t)row * 512 + f0 + (tn << 2)) =
                make_float4(acc[i][0], acc[i][1], acc[i][2], acc[i][3]);
        }
    } else if (blk < eb + 64 + 2512) {       // ---- nsum, 16 shorts/thread ----
        int g = (blk - eb - 64) * 256 + tid;
        int n = g >> 5, c = (g & 31) << 4;
        uint4 o0, o1;
        if (n < NN) {
            const float* r0 = nodes + (size_t)n * 1024 + c;
            const float* r1 = r0 + 512;
            float4 a0 = *(const float4*)(r0 + 0),  a1 = *(const float4*)(r0 + 4);
            float4 a2 = *(const float4*)(r0 + 8),  a3 = *(const float4*)(r0 + 12);
            float4 b0 = *(const float4*)(r1 + 0),  b1 = *(const float4*)(r1 + 4);
            float4 b2 = *(const float4*)(r1 + 8),  b3 = *(const float4*)(r1 + 12);
            o0.x = ((uint32_t)f32_to_bf16(a0.y + b0.y) << 16) | f32_to_bf16(a0.x + b0.x);
            o0.y = ((uint32_t)f32_to_bf16(a0.w + b0.w) << 16) | f32_to_bf16(a0.z + b0.z);
            o0.z = ((uint32_t)f32_to_bf16(a1.y + b1.y) << 16) | f32_to_bf16(a1.x + b1.x);
            o0.w = ((uint32_t)f32_to_bf16(a1.w + b1.w) << 16) | f32_to_bf16(a1.z + b1.z);
            o1.x = ((uint32_t)f32_to_bf16(a2.y + b2.y) << 16) | f32_to_bf16(a2.x + b2.x);
            o1.y = ((uint32_t)f32_to_bf16(a2.w + b2.w) << 16) | f32_to_bf16(a2.z + b2.z);
            o1.z = ((uint32_t)f32_to_bf16(a3.y + b3.y) << 16) | f32_to_bf16(a3.x + b3.x);
            o1.w = ((uint32_t)f32_to_bf16(a3.w + b3.w) << 16) | f32_to_bf16(a3.z + b3.z);
        } else {
            o0 = make_uint4(0, 0, 0, 0); o1 = o0;
        }
        *(uint4*)(nsum16 + (size_t)n * 512 + c) = o0;
        *(uint4*)(nsum16 + (size_t)n * 512 + c + 8) = o1;
    } else if (blk < eb + 64 + 2512 + 32) {  // ---- WT transpose (l=1,2) ----
        unsigned short (*tsh)[68] = (unsigned short(*)[68])shmem;
        int t = blk - eb - 64 - 2512;
        int l = t >> 4, rem = t & 15;
        int c0 = (rem & 3) * 64, r0 = (rem >> 2) * 64;
        const float* inp = gcn_W + (size_t)(l + 1) * 65536;
        unsigned short* outp = WT + (size_t)l * 65536;
        int tx = tid & 15, ty = tid >> 4;
        #pragma unroll
        for (int rr = 0; rr < 4; ++rr) {
            int r = ty * 4 + rr;
            float4 v = *(const float4*)(inp + (size_t)(r0 + r) * 256 + c0 + tx * 4);
            tsh[tx * 4 + 0][r] = f32_to_bf16(v.x);
            tsh[tx * 4 + 1][r] = f32_to_bf16(v.y);
            tsh[tx * 4 + 2][r] = f32_to_bf16(v.z);
            tsh[tx * 4 + 3][r] = f32_to_bf16(v.w);
        }
        __syncthreads();
        #pragma unroll
        for (int cc = 0; cc < 4; ++cc) {
            int c = ty * 4 + cc;
            ushort4 o = *(ushort4*)&tsh[c][tx * 4];
            *(ushort4*)(outp + (size_t)(c0 + c) * 256 + r0 + tx * 4) = o;
        }
    } else {                                 // ---- cvec ----
        int row = (blk - eb - 64 - 2512 - 32) * 4 + (tid >> 6);
        int lane = tid & 63;
        const float* xr = x + (size_t)row * 512;
        float s = 0.f;
        #pragma unroll
        for (int k = 0; k < 512; k += 64) s += xr[k + lane] * bp[k + lane];
        #pragma unroll
        for (int off = 32; off; off >>= 1) s += __shfl_down(s, off);
        if (lane == 0) cvec[row] = 2.0f * s;
    }
}

// ===================== mid: U = T @ Wp (bf16 out) + cb2 = W1^T . cvec ==============
__global__ __launch_bounds__(256) void mid(
    const float* __restrict__ Tf, const float* __restrict__ Wp,
    const float* __restrict__ gcn_W, const float* __restrict__ cvec,
    unsigned short* __restrict__ Ub, float* __restrict__ cb2)
{
    const int blk = blockIdx.x, tid = threadIdx.x;
    if (blk >= 64) {
        int idx = (blk - 64) * 256 + tid;
        int b = idx >> 8, s = idx & 255;
        float sum = 0.f;
        for (int sp = 0; sp < 256; ++sp)
            sum += gcn_W[(size_t)sp * 256 + s] * cvec[b * 256 + sp];
        cb2[idx] = sum;
        return;
    }
    __shared__ float As[16][68];
    __shared__ float Bs[16][64];
    int bm = (blk >> 3) * 64, bn = (blk & 7) * 64;
    int arow = tid >> 2, acol = (tid & 3) << 2;
    int brow = tid >> 4, bcol = (tid & 15) << 2;
    int tm = tid >> 4, tn = tid & 15;
    float acc[4][4] = {};
    for (int k0 = 0; k0 < 512; k0 += 16) {
        float4 av = *(const float4*)(Tf + (size_t)(bm + arow) * 512 + k0 + acol);
        float4 bv = *(const float4*)(Wp + (size_t)(k0 + brow) * 512 + bn + bcol);
        __syncthreads();
        As[acol + 0][arow] = av.x; As[acol + 1][arow] = av.y;
        As[acol + 2][arow] = av.z; As[acol + 3][arow] = av.w;
        *(float4*)&Bs[brow][bcol] = bv;
        __syncthreads();
        #pragma unroll
        for (int k = 0; k < 16; ++k) {
            float a[4], b[4];
            *(float4*)a = *(const float4*)&As[k][tm << 2];
            *(float4*)b = *(const float4*)&Bs[k][tn << 2];
            #pragma unroll
            for (int i = 0; i < 4; ++i)
                #pragma unroll
                for (int j = 0; j < 4; ++j) acc[i][j] += a[i] * b[j];
        }
    }
    #pragma unroll
    for (int i = 0; i < 4; ++i) {
        int row = bm + (tm << 2) + i;
        ushort4 o;
        o.x = f32_to_bf16(acc[i][0]); o.y = f32_to_bf16(acc[i][1]);
        o.z = f32_to_bf16(acc[i][2]); o.w = f32_to_bf16(acc[i][3]);
        *(ushort4*)(Ub + (size_t)row * 512 + bn + (tn << 2)) = o;
    }
}

// ===================== bf16 MFMA GEMM =====================
// C output goes to CHUNKED hw layout: hwc[ch>>6][node][ch&63], ch = global channel
// (0..255 batch0, 256..511 batch1).
// mode 1: hw1: v = (acc + cb2[ch]) * rsqrt(cnt[node]+1), node = m
// mode 2: N=256; b2 = m>=NN, node = m-b2*NN, ch = (b2<<8)+n
__global__ __launch_bounds__(256) void mgemm(
    const unsigned short* __restrict__ A, const unsigned short* __restrict__ BT,
    int K, int N, int mode,
    const float* __restrict__ cb2, const int* __restrict__ cnt,
    unsigned short* __restrict__ C)
{
    __shared__ __align__(16) unsigned short As[128 * 32];
    __shared__ __align__(16) unsigned short Bs[128 * 32];
    const int bm = blockIdx.y * 128, bn = blockIdx.x * 128;
    const int tid = threadIdx.x;
    const int lane = tid & 63, w = tid >> 6;
    const int wm = (w >> 1) << 6, wn = (w & 1) << 6;
    const int r = lane & 15, q = lane >> 4;

    f32x4 acc[4][4] = {};

    for (int k0 = 0; k0 < K; k0 += 32) {
        __syncthreads();
        #pragma unroll
        for (int t = 0; t < 2; ++t) {
            int c = t * 256 + w * 64 + lane;
            int row = c >> 2, col = (c & 3) << 3;
            __builtin_amdgcn_global_load_lds(
                (const __attribute__((address_space(1))) void*)(A + (size_t)(bm + row) * K + k0 + col),
                (__attribute__((address_space(3))) void*)(As + (size_t)(t * 256 + w * 64) * 8),
                16, 0, 0);
            __builtin_amdgcn_global_load_lds(
                (const __attribute__((address_space(1))) void*)(BT + (size_t)(bn + row) * K + k0 + col),
                (__attribute__((address_space(3))) void*)(Bs + (size_t)(t * 256 + w * 64) * 8),
                16, 0, 0);
        }
        __syncthreads();
        frag16 af[4], bf[4];
        #pragma unroll
        for (int i = 0; i < 4; ++i)
            af[i] = *(const frag16*)(As + ((wm + i * 16 + r) << 5) + (q << 3));
        #pragma unroll
        for (int j = 0; j < 4; ++j)
            bf[j] = *(const frag16*)(Bs + ((wn + j * 16 + r) << 5) + (q << 3));
        #pragma unroll
        for (int i = 0; i < 4; ++i)
            #pragma unroll
            for (int j = 0; j < 4; ++j)
                acc[i][j] = __builtin_amdgcn_mfma_f32_16x16x32_bf16(af[i], bf[j], acc[i][j], 0, 0, 0);
    }

    // C/D layout: col = lane&15 (r), row = q*4 + reg
    #pragma unroll
    for (int i = 0; i < 4; ++i) {
        #pragma unroll
        for (int rg = 0; rg < 4; ++rg) {
            int m = bm + wm + i * 16 + (q << 2) + rg;
            float sc;
            int b2 = 0, node = m;
            if (mode == 1) {
                int nc = m > NN - 1 ? NN - 1 : m;
                sc = rsqrtf((float)cnt[nc] + 1.0f);
            } else {
                b2 = m >= NN;
                node = m - b2 * NN;
                int nc = node > NN - 1 ? NN - 1 : node;
                sc = rsqrtf((float)cnt[nc] + 1.0f);
                if (node > 20095) node = 20095;
            }
            #pragma unroll
            for (int j = 0; j < 4; ++j) {
                int n = bn + wn + j * 16 + r;
                int ch, nd;
                float v;
                if (mode == 1) { ch = n; nd = m; v = (acc[i][j][rg] + cb2[n]) * sc; }
                else           { ch = (b2 << 8) + n; nd = node; v = acc[i][j][rg] * sc; }
                C[((size_t)(ch >> 6) * 20096 + nd) * 64 + (ch & 63)] = f32_to_bf16(v);
            }
        }
    }
}

// ===================== GCN aggregation: chunked layout, 4-edge-parallel waves =========
// hwc: [8][20096][64] bf16; chunk ch covers global channels ch*64..+63.
// grid 40000: chunk c = blk & 7 (2.56 MB -> one XCD's L2), node = (blk>>3)*4 + wave.
// Lane: g = lane>>4 (edge subgroup), t = lane&15 (channel quad within chunk).
__global__ __launch_bounds__(256) void aggregate_k(
    const unsigned short* __restrict__ hwc, const int* __restrict__ cnt,
    const int* __restrict__ csr, const float* __restrict__ bias,
    unsigned short* __restrict__ hout,
    const float* __restrict__ w_bp, const float* __restrict__ b_bp,
    float* __restrict__ out)
{
    int blk = blockIdx.x;
    int c = blk & 7;
    int n = (blk >> 3) * 4 + (threadIdx.x >> 6);
    int lane = threadIdx.x & 63;
    int g = lane >> 4, t = lane & 15;
    const unsigned short* base = hwc + (size_t)c * 20096 * 64 + (t << 2);

    float4 acc = make_float4(0.f, 0.f, 0.f, 0.f);
    if (g == 0) acc = dec4(*(const uint2*)(base + (size_t)n * 64));   // self loop
    int deg = cnt[n]; if (deg > 64) deg = 64;
    const int* cp = csr + (n << 6);

    int e = g;
    for (; e + 4 < deg; e += 8) {            // two edges per lane per iter
        int s0 = cp[e], s1 = cp[e + 4];
        float4 f0 = dec4(*(const uint2*)(base + (size_t)s0 * 64));
        float4 f1 = dec4(*(const uint2*)(base + (size_t)s1 * 64));
        acc.x += f0.x + f1.x; acc.y += f0.y + f1.y;
        acc.z += f0.z + f1.z; acc.w += f0.w + f1.w;
    }
    if (e < deg) {
        float4 f = dec4(*(const uint2*)(base + (size_t)cp[e] * 64));
        acc.x += f.x; acc.y += f.y; acc.z += f.z; acc.w += f.w;
    }
    // fold the 4 edge subgroups
    #pragma unroll
    for (int off = 16; off <= 32; off <<= 1) {
        acc.x += __shfl_xor(acc.x, off);
        acc.y += __shfl_xor(acc.y, off);
        acc.z += __shfl_xor(acc.z, off);
        acc.w += __shfl_xor(acc.w, off);
    }

    float dn = rsqrtf((float)deg + 1.0f);
    int s0 = ((c & 3) << 6) + (t << 2);      // channel base within batch
    int b = c >> 2;
    float4 bl = *(const float4*)(bias + s0);
    float4 v;
    v.x = fmaf(dn, acc.x, bl.x); v.y = fmaf(dn, acc.y, bl.y);
    v.z = fmaf(dn, acc.z, bl.z); v.w = fmaf(dn, acc.w, bl.w);
    v.x = v.x > 0.f ? v.x : 0.01f * v.x;
    v.y = v.y > 0.f ? v.y : 0.01f * v.y;
    v.z = v.z > 0.f ? v.z : 0.01f * v.z;
    v.w = v.w > 0.f ? v.w : 0.01f * v.w;

    if (out) {
        float4 w4 = *(const float4*)(w_bp + s0);
        float p = (g == 0) ? (v.x * w4.x + v.y * w4.y + v.z * w4.z + v.w * w4.w) : 0.f;
        #pragma unroll
        for (int off = 32; off; off >>= 1) p += __shfl_xor(p, off);
        if (lane == 0) {
            if ((c & 3) == 0) p += b_bp[0];
            atomicAdd(&out[b * NN + n], p);
        }
    } else if (g == 0) {
        uint2 o;
        o.x = ((uint32_t)f32_to_bf16(v.y) << 16) | f32_to_bf16(v.x);
        o.y = ((uint32_t)f32_to_bf16(v.w) << 16) | f32_to_bf16(v.z);
        *(uint2*)(hout + ((size_t)(b * NN + n)) * 256 + s0) = o;
    }
}

extern "C" void kernel_launch(void* const* d_in, const int* in_sizes, int n_in,
                              void* d_out, int out_size, void* d_ws, size_t ws_size,
                              hipStream_t stream) {
    const float* x     = (const float*)d_in[0];
    const float* nodes = (const float*)d_in[1];
    const int*   eidx  = (const int*)d_in[2];
    const float* Wp    = (const float*)d_in[3];
    const float* bp    = (const float*)d_in[4];
    const float* gcn_W = (const float*)d_in[5];
    const float* gcn_b = (const float*)d_in[6];
    const float* w_bp  = (const float*)d_in[7];
    const float* b_bp  = (const float*)d_in[8];
    const int E = in_sizes[2] / 2;

    char* w = (char*)d_ws;
    auto alloc = [&](size_t bytes) { char* p = w; w += (bytes + 255) & ~(size_t)255; return p; };
    unsigned short* nsum16 = (unsigned short*)alloc((size_t)20096 * 512 * 2);
    unsigned short* hwc    = (unsigned short*)alloc((size_t)8 * 20096 * 64 * 2);
    unsigned short* hA     = (unsigned short*)alloc((size_t)40192 * 256 * 2);
    unsigned short* hB     = (unsigned short*)alloc((size_t)40192 * 256 * 2);
    float* Tf  = (float*)alloc((size_t)512 * 512 * 4);
    unsigned short* Ub = (unsigned short*)alloc((size_t)512 * 512 * 2);
    unsigned short* WT = (unsigned short*)alloc((size_t)2 * 256 * 256 * 2);
    float* cvec = (float*)alloc(512 * 4);
    float* cb2  = (float*)alloc(512 * 4);
    int*   cnt  = (int*)alloc((size_t)NN * 4);
    int*   csr  = (int*)alloc((size_t)NN * 64 * 4);

    hipMemsetAsync(cnt, 0, (size_t)NN * 4, stream);
    hipMemsetAsync(d_out, 0, (size_t)out_size * 4, stream);

    const int cntBlks = (E + 255) / 256;
    prep<<<cntBlks + 64 + 2512 + 32 + 128, 256, 0, stream>>>(
        nodes, x, gcn_W, bp, eidx, eidx + E, nsum16, WT, Tf, cvec, cnt, csr, E);
    mid<<<66, 256, 0, stream>>>(Tf, Wp, gcn_W, cvec, Ub, cb2);

    // hw1 = (nsum @ U^T + cb2) * dinv  -> chunked layout
    mgemm<<<dim3(4, 157), 256, 0, stream>>>(nsum16, Ub, 512, 512, 1, cb2, cnt, hwc);

    aggregate_k<<<40000, 256, 0, stream>>>(hwc, cnt, csr, gcn_b + 0, hA,
                                           w_bp, b_bp, nullptr);
    mgemm<<<dim3(2, 313), 256, 0, stream>>>(hA, WT, 256, 256, 2, nullptr, cnt, hwc);
    aggregate_k<<<40000, 256, 0, stream>>>(hwc, cnt, csr, gcn_b + 256, hB,
                                           w_bp, b_bp, nullptr);
    mgemm<<<dim3(2, 313), 256, 0, stream>>>(hB, WT + 65536, 256, 256, 2, nullptr, cnt, hwc);
    aggregate_k<<<40000, 256, 0, stream>>>(hwc, cnt, csr, gcn_b + 512, nullptr,
                                           w_bp, b_bp, (float*)d_out);
}

// Round 12
// 375.236 us; speedup vs baseline: 1.3183x; 1.2959x over previous
//
#include <hip/hip_runtime.h>
#include <cstddef>
#include <cstdint>

#define NN 20000

typedef short frag16 __attribute__((ext_vector_type(8)));
typedef float f32x4 __attribute__((ext_vector_type(4)));

__device__ inline unsigned short f32_to_bf16(float f) {
    uint32_t u = __float_as_uint(f);
    u += 0x7FFFu + ((u >> 16) & 1u);
    return (unsigned short)(u >> 16);
}

__device__ inline float4 dec4(uint2 v) {
    float4 r;
    r.x = __uint_as_float(v.x << 16);
    r.y = __uint_as_float(v.x & 0xffff0000u);
    r.z = __uint_as_float(v.y << 16);
    r.w = __uint_as_float(v.y & 0xffff0000u);
    return r;
}

// ===================== fused prep =====================
__global__ __launch_bounds__(256) void prep(
    const float* __restrict__ nodes, const float* __restrict__ x,
    const float* __restrict__ gcn_W, const float* __restrict__ bp,
    const int* __restrict__ src, const int* __restrict__ dst,
    unsigned short* __restrict__ nsum16, unsigned short* __restrict__ WT,
    float* __restrict__ Tf, float* __restrict__ cvec,
    int* __restrict__ cnt, int* __restrict__ csr, int E)
{
    __shared__ __align__(16) char shmem[8704];
    const int blk = blockIdx.x, tid = threadIdx.x;
    const int eb = (E + 255) >> 8;

    if (blk < eb) {                          // ---- count + CSR fill ----
        int e = blk * 256 + tid;
        if (e < E) {
            int d = dst[e];
            int pos = atomicAdd(&cnt[d], 1);
            if (pos < 64) csr[(d << 6) + pos] = src[e];
        }
    } else if (blk < eb + 64) {              // ---- T section (fp32) ----
        float* As = (float*)shmem;
        float* Bs = As + 1024;
        int t = blk - eb;
        int b = t >> 5, rem = t & 31;
        int s0 = (rem >> 3) * 64, f0 = (rem & 7) * 64;
        const float* W1 = gcn_W;
        const float* xb = x + (size_t)b * 256 * 512;
        int kk = tid >> 4, c4 = (tid & 15) << 2;
        int tm = tid >> 4, tn = tid & 15;
        float acc[4][4] = {};
        for (int k0 = 0; k0 < 256; k0 += 16) {
            float4 av = *(const float4*)(W1 + (size_t)(k0 + kk) * 256 + s0 + c4);
            float4 bv = *(const float4*)(xb + (size_t)(k0 + kk) * 512 + f0 + c4);
            __syncthreads();
            *(float4*)&As[kk * 64 + c4] = av;
            *(float4*)&Bs[kk * 64 + c4] = bv;
            __syncthreads();
            #pragma unroll
            for (int k = 0; k < 16; ++k) {
                float a[4], bb[4];
                *(float4*)a  = *(const float4*)&As[k * 64 + (tm << 2)];
                *(float4*)bb = *(const float4*)&Bs[k * 64 + (tn << 2)];
                #pragma unroll
                for (int i = 0; i < 4; ++i)
                    #pragma unroll
                    for (int j = 0; j < 4; ++j) acc[i][j] += a[i] * bb[j];
            }
        }
        #pragma unroll
        for (int i = 0; i < 4; ++i) {
            int row = b * 256 + s0 + (tm << 2) + i;
            *(float4*)(Tf + (size_t)row * 512 + f0 + (tn << 2)) =
                make_float4(acc[i][0], acc[i][1], acc[i][2], acc[i][3]);
        }
    } else if (blk < eb + 64 + 2512) {       // ---- nsum, 16 shorts/thread ----
        int g = (blk - eb - 64) * 256 + tid;
        int n = g >> 5, c = (g & 31) << 4;
        uint4 o0, o1;
        if (n < NN) {
            const float* r0 = nodes + (size_t)n * 1024 + c;
            const float* r1 = r0 + 512;
            float4 a0 = *(const float4*)(r0 + 0),  a1 = *(const float4*)(r0 + 4);
            float4 a2 = *(const float4*)(r0 + 8),  a3 = *(const float4*)(r0 + 12);
            float4 b0 = *(const float4*)(r1 + 0),  b1 = *(const float4*)(r1 + 4);
            float4 b2 = *(const float4*)(r1 + 8),  b3 = *(const float4*)(r1 + 12);
            o0.x = ((uint32_t)f32_to_bf16(a0.y + b0.y) << 16) | f32_to_bf16(a0.x + b0.x);
            o0.y = ((uint32_t)f32_to_bf16(a0.w + b0.w) << 16) | f32_to_bf16(a0.z + b0.z);
            o0.z = ((uint32_t)f32_to_bf16(a1.y + b1.y) << 16) | f32_to_bf16(a1.x + b1.x);
            o0.w = ((uint32_t)f32_to_bf16(a1.w + b1.w) << 16) | f32_to_bf16(a1.z + b1.z);
            o1.x = ((uint32_t)f32_to_bf16(a2.y + b2.y) << 16) | f32_to_bf16(a2.x + b2.x);
            o1.y = ((uint32_t)f32_to_bf16(a2.w + b2.w) << 16) | f32_to_bf16(a2.z + b2.z);
            o1.z = ((uint32_t)f32_to_bf16(a3.y + b3.y) << 16) | f32_to_bf16(a3.x + b3.x);
            o1.w = ((uint32_t)f32_to_bf16(a3.w + b3.w) << 16) | f32_to_bf16(a3.z + b3.z);
        } else {
            o0 = make_uint4(0, 0, 0, 0); o1 = o0;
        }
        *(uint4*)(nsum16 + (size_t)n * 512 + c) = o0;
        *(uint4*)(nsum16 + (size_t)n * 512 + c + 8) = o1;
    } else if (blk < eb + 64 + 2512 + 32) {  // ---- WT transpose (l=1,2) ----
        unsigned short (*tsh)[68] = (unsigned short(*)[68])shmem;
        int t = blk - eb - 64 - 2512;
        int l = t >> 4, rem = t & 15;
        int c0 = (rem & 3) * 64, r0 = (rem >> 2) * 64;
        const float* inp = gcn_W + (size_t)(l + 1) * 65536;
        unsigned short* outp = WT + (size_t)l * 65536;
        int tx = tid & 15, ty = tid >> 4;
        #pragma unroll
        for (int rr = 0; rr < 4; ++rr) {
            int r = ty * 4 + rr;
            float4 v = *(const float4*)(inp + (size_t)(r0 + r) * 256 + c0 + tx * 4);
            tsh[tx * 4 + 0][r] = f32_to_bf16(v.x);
            tsh[tx * 4 + 1][r] = f32_to_bf16(v.y);
            tsh[tx * 4 + 2][r] = f32_to_bf16(v.z);
            tsh[tx * 4 + 3][r] = f32_to_bf16(v.w);
        }
        __syncthreads();
        #pragma unroll
        for (int cc = 0; cc < 4; ++cc) {
            int c = ty * 4 + cc;
            ushort4 o = *(ushort4*)&tsh[c][tx * 4];
            *(ushort4*)(outp + (size_t)(c0 + c) * 256 + r0 + tx * 4) = o;
        }
    } else {                                 // ---- cvec ----
        int row = (blk - eb - 64 - 2512 - 32) * 4 + (tid >> 6);
        int lane = tid & 63;
        const float* xr = x + (size_t)row * 512;
        float s = 0.f;
        #pragma unroll
        for (int k = 0; k < 512; k += 64) s += xr[k + lane] * bp[k + lane];
        #pragma unroll
        for (int off = 32; off; off >>= 1) s += __shfl_down(s, off);
        if (lane == 0) cvec[row] = 2.0f * s;
    }
}

// ===================== mid: U = T @ Wp (bf16 out) + cb2 = W1^T . cvec ==============
__global__ __launch_bounds__(256) void mid(
    const float* __restrict__ Tf, const float* __restrict__ Wp,
    const float* __restrict__ gcn_W, const float* __restrict__ cvec,
    unsigned short* __restrict__ Ub, float* __restrict__ cb2)
{
    const int blk = blockIdx.x, tid = threadIdx.x;
    if (blk >= 64) {
        int idx = (blk - 64) * 256 + tid;
        int b = idx >> 8, s = idx & 255;
        float sum = 0.f;
        for (int sp = 0; sp < 256; ++sp)
            sum += gcn_W[(size_t)sp * 256 + s] * cvec[b * 256 + sp];
        cb2[idx] = sum;
        return;
    }
    __shared__ float As[16][68];
    __shared__ float Bs[16][64];
    int bm = (blk >> 3) * 64, bn = (blk & 7) * 64;
    int arow = tid >> 2, acol = (tid & 3) << 2;
    int brow = tid >> 4, bcol = (tid & 15) << 2;
    int tm = tid >> 4, tn = tid & 15;
    float acc[4][4] = {};
    for (int k0 = 0; k0 < 512; k0 += 16) {
        float4 av = *(const float4*)(Tf + (size_t)(bm + arow) * 512 + k0 + acol);
        float4 bv = *(const float4*)(Wp + (size_t)(k0 + brow) * 512 + bn + bcol);
        __syncthreads();
        As[acol + 0][arow] = av.x; As[acol + 1][arow] = av.y;
        As[acol + 2][arow] = av.z; As[acol + 3][arow] = av.w;
        *(float4*)&Bs[brow][bcol] = bv;
        __syncthreads();
        #pragma unroll
        for (int k = 0; k < 16; ++k) {
            float a[4], b[4];
            *(float4*)a = *(const float4*)&As[k][tm << 2];
            *(float4*)b = *(const float4*)&Bs[k][tn << 2];
            #pragma unroll
            for (int i = 0; i < 4; ++i)
                #pragma unroll
                for (int j = 0; j < 4; ++j) acc[i][j] += a[i] * b[j];
        }
    }
    #pragma unroll
    for (int i = 0; i < 4; ++i) {
        int row = bm + (tm << 2) + i;
        ushort4 o;
        o.x = f32_to_bf16(acc[i][0]); o.y = f32_to_bf16(acc[i][1]);
        o.z = f32_to_bf16(acc[i][2]); o.w = f32_to_bf16(acc[i][3]);
        *(ushort4*)(Ub + (size_t)row * 512 + bn + (tn << 2)) = o;
    }
}

// ===================== bf16 MFMA GEMM =====================
// C = A[M,K] @ BT[N,K]^T, bf16 in/out, fp32 accum. hw layout: [node][512] interleaved
// (cols 0..255 batch0, 256..511 batch1).
// mode 1: hw1: C[m*512+n] = (acc + cb2[n]) * rsqrt(cnt[m]+1)   (m = node)
// mode 2: N=256; b2 = m>=NN, node=m-b2*NN; C[node*512+(b2<<8)+n] = acc*rsqrt(cnt[node]+1)
__global__ __launch_bounds__(256) void mgemm(
    const unsigned short* __restrict__ A, const unsigned short* __restrict__ BT,
    int K, int N, int mode,
    const float* __restrict__ cb2, const int* __restrict__ cnt,
    unsigned short* __restrict__ C)
{
    __shared__ __align__(16) unsigned short As[128 * 32];
    __shared__ __align__(16) unsigned short Bs[128 * 32];
    const int bm = blockIdx.y * 128, bn = blockIdx.x * 128;
    const int tid = threadIdx.x;
    const int lane = tid & 63, w = tid >> 6;
    const int wm = (w >> 1) << 6, wn = (w & 1) << 6;
    const int r = lane & 15, q = lane >> 4;

    f32x4 acc[4][4] = {};

    for (int k0 = 0; k0 < K; k0 += 32) {
        __syncthreads();
        #pragma unroll
        for (int t = 0; t < 2; ++t) {
            int c = t * 256 + w * 64 + lane;
            int row = c >> 2, col = (c & 3) << 3;
            __builtin_amdgcn_global_load_lds(
                (const __attribute__((address_space(1))) void*)(A + (size_t)(bm + row) * K + k0 + col),
                (__attribute__((address_space(3))) void*)(As + (size_t)(t * 256 + w * 64) * 8),
                16, 0, 0);
            __builtin_amdgcn_global_load_lds(
                (const __attribute__((address_space(1))) void*)(BT + (size_t)(bn + row) * K + k0 + col),
                (__attribute__((address_space(3))) void*)(Bs + (size_t)(t * 256 + w * 64) * 8),
                16, 0, 0);
        }
        __syncthreads();
        frag16 af[4], bf[4];
        #pragma unroll
        for (int i = 0; i < 4; ++i)
            af[i] = *(const frag16*)(As + ((wm + i * 16 + r) << 5) + (q << 3));
        #pragma unroll
        for (int j = 0; j < 4; ++j)
            bf[j] = *(const frag16*)(Bs + ((wn + j * 16 + r) << 5) + (q << 3));
        #pragma unroll
        for (int i = 0; i < 4; ++i)
            #pragma unroll
            for (int j = 0; j < 4; ++j)
                acc[i][j] = __builtin_amdgcn_mfma_f32_16x16x32_bf16(af[i], bf[j], acc[i][j], 0, 0, 0);
    }

    // C/D layout: col = lane&15 (r), row = q*4 + reg
    #pragma unroll
    for (int i = 0; i < 4; ++i) {
        #pragma unroll
        for (int rg = 0; rg < 4; ++rg) {
            int m = bm + wm + i * 16 + (q << 2) + rg;
            float sc;
            int b2 = 0, node = m;
            if (mode == 1) {
                int nc = m > NN - 1 ? NN - 1 : m;
                sc = rsqrtf((float)cnt[nc] + 1.0f);
            } else {
                b2 = m >= NN;
                node = m - b2 * NN;
                int nc = node > NN - 1 ? NN - 1 : node;
                sc = rsqrtf((float)cnt[nc] + 1.0f);
                if (node > 20095) node = 20095;
            }
            #pragma unroll
            for (int j = 0; j < 4; ++j) {
                int n = bn + wn + j * 16 + r;
                if (mode == 1) {
                    float v = (acc[i][j][rg] + cb2[n]) * sc;
                    C[(size_t)m * 512 + n] = f32_to_bf16(v);
                } else {
                    float v = acc[i][j][rg] * sc;
                    C[(size_t)node * 512 + (b2 << 8) + n] = f32_to_bf16(v);
                }
            }
        }
    }
}

// ===================== GCN aggregation (batch-sliced, csr-broadcast) ================
// hw: [20096][512] bf16, cols 0..255 b0, 256..511 b1, rows pre-scaled by dinv[src].
// grid (5000, 2): y = batch. One wave per node; uint2 8B slice loads.
// csr indices preloaded one-per-lane, distributed via __shfl -> gathers pipeline freely.
__global__ __launch_bounds__(256) void aggregate_s(
    const unsigned short* __restrict__ hw, const int* __restrict__ cnt,
    const int* __restrict__ csr, const float* __restrict__ bias,
    unsigned short* __restrict__ hout,
    const float* __restrict__ w_bp, const float* __restrict__ b_bp,
    float* __restrict__ out)
{
    int n = blockIdx.x * 4 + (threadIdx.x >> 6);   // node 0..19999
    int b = blockIdx.y;
    int lane = threadIdx.x & 63;
    const unsigned short* rowp = hw + (b << 8) + (lane << 2);

    int deg = cnt[n]; if (deg > 64) deg = 64;
    int myidx = csr[(n << 6) + lane];              // all 64 slots (garbage past deg)

    float4 acc = dec4(*(const uint2*)(rowp + (size_t)n * 512));   // self loop
    int e = 0;
    for (; e + 8 <= deg; e += 8) {
        int s0 = __shfl(myidx, e + 0), s1 = __shfl(myidx, e + 1);
        int s2 = __shfl(myidx, e + 2), s3 = __shfl(myidx, e + 3);
        int s4 = __shfl(myidx, e + 4), s5 = __shfl(myidx, e + 5);
        int s6 = __shfl(myidx, e + 6), s7 = __shfl(myidx, e + 7);
        uint2 u0 = *(const uint2*)(rowp + (size_t)s0 * 512);
        uint2 u1 = *(const uint2*)(rowp + (size_t)s1 * 512);
        uint2 u2 = *(const uint2*)(rowp + (size_t)s2 * 512);
        uint2 u3 = *(const uint2*)(rowp + (size_t)s3 * 512);
        uint2 u4 = *(const uint2*)(rowp + (size_t)s4 * 512);
        uint2 u5 = *(const uint2*)(rowp + (size_t)s5 * 512);
        uint2 u6 = *(const uint2*)(rowp + (size_t)s6 * 512);
        uint2 u7 = *(const uint2*)(rowp + (size_t)s7 * 512);
        float4 f0 = dec4(u0), f1 = dec4(u1), f2 = dec4(u2), f3 = dec4(u3);
        float4 f4 = dec4(u4), f5 = dec4(u5), f6 = dec4(u6), f7 = dec4(u7);
        acc.x += ((f0.x + f1.x) + (f2.x + f3.x)) + ((f4.x + f5.x) + (f6.x + f7.x));
        acc.y += ((f0.y + f1.y) + (f2.y + f3.y)) + ((f4.y + f5.y) + (f6.y + f7.y));
        acc.z += ((f0.z + f1.z) + (f2.z + f3.z)) + ((f4.z + f5.z) + (f6.z + f7.z));
        acc.w += ((f0.w + f1.w) + (f2.w + f3.w)) + ((f4.w + f5.w) + (f6.w + f7.w));
    }
    if (e + 4 <= deg) {
        int s0 = __shfl(myidx, e + 0), s1 = __shfl(myidx, e + 1);
        int s2 = __shfl(myidx, e + 2), s3 = __shfl(myidx, e + 3);
        uint2 u0 = *(const uint2*)(rowp + (size_t)s0 * 512);
        uint2 u1 = *(const uint2*)(rowp + (size_t)s1 * 512);
        uint2 u2 = *(const uint2*)(rowp + (size_t)s2 * 512);
        uint2 u3 = *(const uint2*)(rowp + (size_t)s3 * 512);
        float4 f0 = dec4(u0), f1 = dec4(u1), f2 = dec4(u2), f3 = dec4(u3);
        acc.x += (f0.x + f1.x) + (f2.x + f3.x);
        acc.y += (f0.y + f1.y) + (f2.y + f3.y);
        acc.z += (f0.z + f1.z) + (f2.z + f3.z);
        acc.w += (f0.w + f1.w) + (f2.w + f3.w);
        e += 4;
    }
    for (; e < deg; ++e) {
        int s0 = __shfl(myidx, e);
        float4 f = dec4(*(const uint2*)(rowp + (size_t)s0 * 512));
        acc.x += f.x; acc.y += f.y; acc.z += f.z; acc.w += f.w;
    }

    float dn = rsqrtf((float)deg + 1.0f);
    int s = lane << 2;
    float4 bl = *(const float4*)(bias + s);
    float4 v;
    v.x = fmaf(dn, acc.x, bl.x); v.y = fmaf(dn, acc.y, bl.y);
    v.z = fmaf(dn, acc.z, bl.z); v.w = fmaf(dn, acc.w, bl.w);
    v.x = v.x > 0.f ? v.x : 0.01f * v.x;
    v.y = v.y > 0.f ? v.y : 0.01f * v.y;
    v.z = v.z > 0.f ? v.z : 0.01f * v.z;
    v.w = v.w > 0.f ? v.w : 0.01f * v.w;

    if (out) {
        float4 w4 = *(const float4*)(w_bp + s);
        float sum = v.x * w4.x + v.y * w4.y + v.z * w4.z + v.w * w4.w;
        #pragma unroll
        for (int off = 32; off; off >>= 1) sum += __shfl_xor(sum, off);
        if (lane == 0) out[b * NN + n] = sum + b_bp[0];
    } else {
        uint2 o;
        o.x = ((uint32_t)f32_to_bf16(v.y) << 16) | f32_to_bf16(v.x);
        o.y = ((uint32_t)f32_to_bf16(v.w) << 16) | f32_to_bf16(v.z);
        *(uint2*)(hout + ((size_t)(b * NN + n)) * 256 + s) = o;
    }
}

extern "C" void kernel_launch(void* const* d_in, const int* in_sizes, int n_in,
                              void* d_out, int out_size, void* d_ws, size_t ws_size,
                              hipStream_t stream) {
    const float* x     = (const float*)d_in[0];
    const float* nodes = (const float*)d_in[1];
    const int*   eidx  = (const int*)d_in[2];
    const float* Wp    = (const float*)d_in[3];
    const float* bp    = (const float*)d_in[4];
    const float* gcn_W = (const float*)d_in[5];
    const float* gcn_b = (const float*)d_in[6];
    const float* w_bp  = (const float*)d_in[7];
    const float* b_bp  = (const float*)d_in[8];
    const int E = in_sizes[2] / 2;

    char* w = (char*)d_ws;
    auto alloc = [&](size_t bytes) { char* p = w; w += (bytes + 255) & ~(size_t)255; return p; };
    unsigned short* nsum16 = (unsigned short*)alloc((size_t)20096 * 512 * 2);
    unsigned short* hw16   = (unsigned short*)alloc((size_t)20096 * 512 * 2);
    unsigned short* hA     = (unsigned short*)alloc((size_t)40192 * 256 * 2);
    unsigned short* hB     = (unsigned short*)alloc((size_t)40192 * 256 * 2);
    float* Tf  = (float*)alloc((size_t)512 * 512 * 4);
    unsigned short* Ub = (unsigned short*)alloc((size_t)512 * 512 * 2);
    unsigned short* WT = (unsigned short*)alloc((size_t)2 * 256 * 256 * 2);
    float* cvec = (float*)alloc(512 * 4);
    float* cb2  = (float*)alloc(512 * 4);
    int*   cnt  = (int*)alloc((size_t)NN * 4);
    int*   csr  = (int*)alloc((size_t)NN * 64 * 4);

    hipMemsetAsync(cnt, 0, (size_t)NN * 4, stream);

    const int cntBlks = (E + 255) / 256;
    prep<<<cntBlks + 64 + 2512 + 32 + 128, 256, 0, stream>>>(
        nodes, x, gcn_W, bp, eidx, eidx + E, nsum16, WT, Tf, cvec, cnt, csr, E);
    mid<<<66, 256, 0, stream>>>(Tf, Wp, gcn_W, cvec, Ub, cb2);

    // hw1[node,(b,s)] = (nsum @ U^T + cb2) * dinv[node]
    mgemm<<<dim3(4, 157), 256, 0, stream>>>(nsum16, Ub, 512, 512, 1, cb2, cnt, hw16);

    aggregate_s<<<dim3(5000, 2), 256, 0, stream>>>(hw16, cnt, csr, gcn_b + 0, hA,
                                                   w_bp, b_bp, nullptr);
    mgemm<<<dim3(2, 313), 256, 0, stream>>>(hA, WT, 256, 256, 2, nullptr, cnt, hw16);
    aggregate_s<<<dim3(5000, 2), 256, 0, stream>>>(hw16, cnt, csr, gcn_b + 256, hB,
                                                   w_bp, b_bp, nullptr);
    mgemm<<<dim3(2, 313), 256, 0, stream>>>(hB, WT + 65536, 256, 256, 2, nullptr, cnt, hw16);
    aggregate_s<<<dim3(5000, 2), 256, 0, stream>>>(hw16, cnt, csr, gcn_b + 512, nullptr,
                                                   w_bp, b_bp, (float*)d_out);
}